// Round 6
// baseline (355.960 us; speedup 1.0000x reference)
//
#include <hip/hip_runtime.h>
#include <math.h>

#define HEADS 4
#define KB 8
#define Bsz 8
#define Nn 10000
#define Hh 512
#define HD 128   // head dim = Hh/HEADS
#define NPART 128

// ws layout (float offsets)
#define KSUM_OFF 4096      // [B][H]        4096
#define VSUM_OFF 8192      // [B][H]        4096
#define WQE_OFF  12288     // [B][4][H]    16384
#define WOE_OFF  28672     // [B][4][H]    16384
#define ESUM_OFF 45056     // [4][8]          32
#define FSUM_OFF 45088     // [4][8]          32
#define BQ_OFF   45120     // [B][4]          32
#define BD_OFF   45152     // [4][8]          32
#define XPART_OFF 45184                        // [NPART][B][Hh] = 524288 floats
#define EFPART_OFF (XPART_OFF + NPART * Bsz * Hh)
#define WS_NEED   (EFPART_OFF + 512)

typedef float f32x4_t __attribute__((ext_vector_type(4)));

// ---------------- K1: partial sums (atomic-free) ----------------
// x branch: float4/lane (16B = measured BW sweet spot); 256 thr cover 2 rows
// per iter via row parity, combined through LDS at the end.
__global__ __launch_bounds__(256) void k_part(const float* __restrict__ x,
                                              const float* __restrict__ E,
                                              const float* __restrict__ Fp,
                                              float* __restrict__ xpart,
                                              float* __restrict__ efpart) {
    int blk = blockIdx.x;
    int t = threadIdx.x;
    __shared__ float4 sd4[256];
    if (blk < NPART * Bsz) {
        int p = blk >> 3, b = blk & 7;
        const int CH = (Nn + NPART - 1) / NPART;  // 79
        int n0 = p * CH, n1 = min(n0 + CH, Nn);
        int half = t >> 7;            // row parity
        int c = (t & 127) * 4;        // column (float4)
        float4 acc = {0.f, 0.f, 0.f, 0.f};
        const float* base = x + (size_t)b * Nn * Hh + c;
#pragma unroll 4
        for (int n = n0 + half; n < n1; n += 2) {
            float4 v = *(const float4*)(base + (size_t)n * Hh);
            acc.x += v.x; acc.y += v.y; acc.z += v.z; acc.w += v.w;
        }
        sd4[t] = acc;
        __syncthreads();
        if (t < 128) {
            float4 o = sd4[t], q = sd4[t + 128];
            o.x += q.x; o.y += q.y; o.z += q.z; o.w += q.w;
            *(float4*)(xpart + (size_t)(p * Bsz + b) * Hh + t * 4) = o;
        }
    } else {
        int idx = blk - NPART * Bsz;  // 0..63
        int src = idx >> 5, h = (idx >> 3) & 3, ch = idx & 7;
        const float* S = src ? Fp : E;
        const int CHE = Nn / 8;  // 1250
        int n0 = ch * CHE, n1 = n0 + CHE;
        int kk = t & 7, part = t >> 3;  // 32 parts
        float acc = 0.f;
        const float* base = S + (size_t)h * Nn * KB;
#pragma unroll 4
        for (int n = n0 + part; n < n1; n += 32) acc += base[n * KB + kk];
        float* sd = (float*)sd4;
        sd[t] = acc;
        __syncthreads();
        for (int s = 128; s >= 8; s >>= 1) {
            if (t < s) sd[t] += sd[t + s];
            __syncthreads();
        }
        if (t < 8) efpart[idx * 8 + t] = sd[t];
    }
}

// ---------------- K2: reduce partials ----------------
__global__ __launch_bounds__(256) void k_reduce(const float* __restrict__ xpart,
                                                const float* __restrict__ efpart,
                                                float* __restrict__ xs,
                                                float* __restrict__ esum,
                                                float* __restrict__ fsum) {
    int blk = blockIdx.x, t = threadIdx.x;
    if (blk < 16) {
        int o = blk * 256 + t;  // b*512 + c
        float a = 0.f;
#pragma unroll 8
        for (int p = 0; p < NPART; ++p) a += xpart[(size_t)p * (Bsz * Hh) + o];
        xs[o] = a;
    } else if (t < 64) {
        int src = t >> 5, rem = t & 31;  // rem = h*8+kk
        float a = 0.f;
#pragma unroll
        for (int ch = 0; ch < 8; ++ch)
            a += efpart[((src * 4 + (rem >> 3)) * 8 + ch) * 8 + (rem & 7)];
        if (src == 0) esum[rem] = a; else fsum[rem] = a;
    }
}

// ---------------- K3: ksum[b,r] = sum_c Wk[r,c]*xs[b,c] + N*bk[r] ----------------
// grid (2, 32): m selects K/V matrix, rg covers 16 rows; xs register-resident,
// folded butterfly reduces all 8 batches in 10 shuffles.
__global__ __launch_bounds__(256) void k_gemv(const float* __restrict__ Wk,
                                              const float* __restrict__ bk,
                                              const float* __restrict__ Wv,
                                              const float* __restrict__ bv,
                                              const float* __restrict__ xs,
                                              float* __restrict__ ksum,
                                              float* __restrict__ vsum) {
    int m = blockIdx.x;
    int rg = blockIdx.y;  // 0..31
    const float* W = m ? Wv : Wk;
    const float* bias = m ? bv : bk;
    float* outp = m ? vsum : ksum;
    int t = threadIdx.x;
    int wid = t >> 6, lane = t & 63;
    bool hi32 = (lane & 32) != 0;
    bool hi16 = (lane & 16) != 0;
    bool hi8  = (lane & 8) != 0;

    float4 x0[Bsz], x1[Bsz];
#pragma unroll
    for (int b = 0; b < Bsz; ++b) {
        x0[b] = *(const float4*)(xs + b * Hh + lane * 4);
        x1[b] = *(const float4*)(xs + b * Hh + 256 + lane * 4);
    }
#pragma unroll
    for (int i = 0; i < 4; ++i) {
        int r = rg * 16 + wid + 4 * i;
        float4 wa = *(const float4*)(W + (size_t)r * Hh + lane * 4);
        float4 wb = *(const float4*)(W + (size_t)r * Hh + 256 + lane * 4);
        float p[Bsz];
#pragma unroll
        for (int b = 0; b < Bsz; ++b) {
            p[b] = wa.x * x0[b].x + wa.y * x0[b].y + wa.z * x0[b].z + wa.w * x0[b].w +
                   wb.x * x1[b].x + wb.y * x1[b].y + wb.z * x1[b].z + wb.w * x1[b].w;
        }
        // fold 8 accumulators across the wave: lane-group g = lane>>3 ends with batch b=g.
        float a, bb;
        a = hi32 ? p[4] : p[0]; bb = hi32 ? p[0] : p[4]; float q0 = a + __shfl_xor(bb, 32, 64);
        a = hi32 ? p[5] : p[1]; bb = hi32 ? p[1] : p[5]; float q1 = a + __shfl_xor(bb, 32, 64);
        a = hi32 ? p[6] : p[2]; bb = hi32 ? p[2] : p[6]; float q2 = a + __shfl_xor(bb, 32, 64);
        a = hi32 ? p[7] : p[3]; bb = hi32 ? p[3] : p[7]; float q3 = a + __shfl_xor(bb, 32, 64);
        a = hi16 ? q2 : q0; bb = hi16 ? q0 : q2; float r0 = a + __shfl_xor(bb, 16, 64);
        a = hi16 ? q3 : q1; bb = hi16 ? q1 : q3; float r1 = a + __shfl_xor(bb, 16, 64);
        a = hi8 ? r1 : r0; bb = hi8 ? r0 : r1; float s = a + __shfl_xor(bb, 8, 64);
        s += __shfl_xor(s, 4, 64);
        s += __shfl_xor(s, 2, 64);
        s += __shfl_xor(s, 1, 64);
        if ((lane & 7) == 0) {
            int b = lane >> 3;
            outp[b * Hh + r] = s + (float)Nn * bias[r];
        }
    }
}

// ---------------- K4: wq_eff / wo_eff + (block 64) bias_q, bias_diag, reg ----------------
// unroll 16 on the Wq column walk (32 loads in flight vs 8 against ~900cy
// cold-HBM latency), float4 + unroll 8 on the Wo row walk.
__global__ __launch_bounds__(256) void k_eff2(const float* __restrict__ Wq,
                                              const float* __restrict__ Wo,
                                              const float* __restrict__ ksum,
                                              const float* __restrict__ vsum,
                                              float* __restrict__ wqe,
                                              float* __restrict__ woe,
                                              const float* __restrict__ bq,
                                              const float* __restrict__ gbu,
                                              const float* __restrict__ gbv,
                                              const float* __restrict__ log_reg,
                                              float* __restrict__ bias_q,
                                              float* __restrict__ bias_diag,
                                              float* __restrict__ reg_out) {
    int blk = blockIdx.x;
    int t = threadIdx.x;
    __shared__ float sL[256];
    if (blk < 64) {
        int b = blk >> 3, rem = blk & 7, h = rem >> 1, m = rem & 1;
        const float* s = (m ? vsum : ksum) + b * Hh + h * HD;
        float* out = (m ? woe : wqe) + (size_t)(b * HEADS + h) * Hh;
        if (t < HD) sL[t] = s[t];
        __syncthreads();
        float a0 = 0.f, a1 = 0.f;
        if (m == 0) {
            const float* Wb = Wq + (size_t)h * HD * Hh;
#pragma unroll 16
            for (int d = 0; d < HD; ++d) {
                float sv = sL[d];
                a0 += Wb[(size_t)d * Hh + t] * sv;
                a1 += Wb[(size_t)d * Hh + t + 256] * sv;
            }
        } else {
            const float4* W0 = (const float4*)(Wo + (size_t)t * Hh + h * HD);
            const float4* W1 = (const float4*)(Wo + (size_t)(t + 256) * Hh + h * HD);
#pragma unroll 8
            for (int d = 0; d < HD; d += 4) {
                float4 w0 = W0[d >> 2];
                float4 w1 = W1[d >> 2];
                a0 += w0.x * sL[d] + w0.y * sL[d + 1] + w0.z * sL[d + 2] + w0.w * sL[d + 3];
                a1 += w1.x * sL[d] + w1.y * sL[d + 1] + w1.z * sL[d + 2] + w1.w * sL[d + 3];
            }
        }
        out[t] = a0;
        out[t + 256] = a1;
    } else {
        int h = t >> 6, i = (t >> 3) & 7, j = t & 7;
        float gb = 0.f;
#pragma unroll
        for (int l = 0; l < 8; ++l) gb += gbu[h * 64 + i * 8 + l] * gbv[h * 64 + l * 8 + j];
        if (i == j) bias_diag[h * 8 + i] = gb;
        sL[t] = fabsf(gb);
        __syncthreads();
        for (int s = 128; s >= 1; s >>= 1) {
            if (t < s) sL[t] += sL[t + s];
            __syncthreads();
        }
        if (t == 0) {
            float gbmean = sL[0] / 256.f;
            reg_out[0] = expf(log_reg[0]) * (0.125f + gbmean * 0.1f);
        }
        if (t < 32) {
            int b = t >> 2, hh = t & 3;
            float a = 0.f;
            for (int d = 0; d < HD; ++d) a += bq[hh * HD + d] * ksum[b * Hh + hh * HD + d];
            bias_q[t] = a;  // [b][h]
        }
    }
}

// ---------------- K5: main pass (no LDS, all weights in registers) ----------------
// grid (250, B), block 256 = 4 waves; wave-per-row. Software-pipelined x loads
// (prefetch row j+1 before computing row j). Non-temporal stores so the
// out-write does not evict x from L3.
__global__ __launch_bounds__(256) void k_main(const float* __restrict__ x,
                                              const float* __restrict__ bo,
                                              const float* __restrict__ wqe,
                                              const float* __restrict__ woe,
                                              const float* __restrict__ esum,
                                              const float* __restrict__ fsum,
                                              const float* __restrict__ bias_q,
                                              const float* __restrict__ bias_diag,
                                              float* __restrict__ out) {
    int b = blockIdx.y;
    int t = threadIdx.x;
    int wid = t >> 6, lane = t & 63;

    const float* wqe_b = wqe + (size_t)b * HEADS * Hh;
    const float* woe_b = woe + (size_t)b * HEADS * Hh;
    float4 wqa[HEADS], wqb[HEADS], woa[HEADS], wob[HEADS];
#pragma unroll
    for (int h = 0; h < HEADS; ++h) {
        wqa[h] = *(const float4*)(wqe_b + h * Hh + lane * 4);
        wqb[h] = *(const float4*)(wqe_b + h * Hh + 256 + lane * 4);
        woa[h] = *(const float4*)(woe_b + h * Hh + lane * 4);
        wob[h] = *(const float4*)(woe_b + h * Hh + 256 + lane * 4);
    }
    float4 boa = *(const float4*)(bo + lane * 4);
    float4 bob = *(const float4*)(bo + 256 + lane * 4);

    // quadrant softmax mapping: quadrant q = lane>>4 holds head hq = {0,2,1,3}[q]
    int q = lane >> 4;
    int hq = (q == 0) ? 0 : (q == 1) ? 2 : (q == 2) ? 1 : 3;
    int kk = lane & 7;
    float eV = esum[hq * KB + kk];
    float fV = fsum[hq * KB + kk];
    float bdV = bias_diag[hq * KB + kk];
    float bqV = bias_q[b * HEADS + hq];

    const float inv_sqrt_hd = 0.08838834764831843f;  // 1/sqrt(128)
    bool hi32 = (lane & 32) != 0;
    bool hi16 = (lane & 16) != 0;

    int n = blockIdx.x * 4 + wid;  // grid.x == 250 -> step 1000, exactly 10 rows/wave
    const float* xr0 = x + ((size_t)b * Nn + n) * Hh;
    float4 xa = *(const float4*)(xr0 + lane * 4);
    float4 xb = *(const float4*)(xr0 + 256 + lane * 4);
#pragma unroll 2
    for (int j = 0; j < 10; ++j) {
        int ncur = n;
        float4 ca = xa, cb = xb;
        n += 1000;
        if (j < 9) {  // prefetch next row
            const float* xr = x + ((size_t)b * Nn + n) * Hh;
            xa = *(const float4*)(xr + lane * 4);
            xb = *(const float4*)(xr + 256 + lane * 4);
        }
        float p[HEADS];
#pragma unroll
        for (int h = 0; h < HEADS; ++h) {
            p[h] = ca.x * wqa[h].x + ca.y * wqa[h].y + ca.z * wqa[h].z + ca.w * wqa[h].w +
                   cb.x * wqb[h].x + cb.y * wqb[h].y + cb.z * wqb[h].z + cb.w * wqb[h].w;
        }
        // folded butterfly: 7 shfl instead of 24.
        float A  = hi32 ? p[1] : p[0];
        float Bv = hi32 ? p[0] : p[1];
        A += __shfl_xor(Bv, 32, 64);
        float C  = hi32 ? p[3] : p[2];
        float D  = hi32 ? p[2] : p[3];
        C += __shfl_xor(D, 32, 64);
        float Ev = hi16 ? C : A;
        float Fv = hi16 ? A : C;
        Ev += __shfl_xor(Fv, 16, 64);
        Ev += __shfl_xor(Ev, 1, 64);
        Ev += __shfl_xor(Ev, 2, 64);
        Ev += __shfl_xor(Ev, 4, 64);
        Ev += __shfl_xor(Ev, 8, 64);
        // Ev = full 64-lane dot for head hq, identical across the quadrant

        float sq = (Ev + bqV) * inv_sqrt_hd;
        float sc = eV * sq + bdV;
        float m = sc;
        m = fmaxf(m, __shfl_xor(m, 1, 64));
        m = fmaxf(m, __shfl_xor(m, 2, 64));
        m = fmaxf(m, __shfl_xor(m, 4, 64));
        float e = __expf(sc - m);
        float se = e, sw = e * fV;
        se += __shfl_xor(se, 1, 64); sw += __shfl_xor(sw, 1, 64);
        se += __shfl_xor(se, 2, 64); sw += __shfl_xor(sw, 2, 64);
        se += __shfl_xor(se, 4, 64); sw += __shfl_xor(sw, 4, 64);
        float wv = __fdividef(sw, se);
        float w0 = __shfl(wv, 0, 64);
        float w2 = __shfl(wv, 16, 64);
        float w1 = __shfl(wv, 32, 64);
        float w3 = __shfl(wv, 48, 64);

        float4 oa = boa, ob = bob;
        oa.x += w0 * woa[0].x + w1 * woa[1].x + w2 * woa[2].x + w3 * woa[3].x;
        oa.y += w0 * woa[0].y + w1 * woa[1].y + w2 * woa[2].y + w3 * woa[3].y;
        oa.z += w0 * woa[0].z + w1 * woa[1].z + w2 * woa[2].z + w3 * woa[3].z;
        oa.w += w0 * woa[0].w + w1 * woa[1].w + w2 * woa[2].w + w3 * woa[3].w;
        ob.x += w0 * wob[0].x + w1 * wob[1].x + w2 * wob[2].x + w3 * wob[3].x;
        ob.y += w0 * wob[0].y + w1 * wob[1].y + w2 * wob[2].y + w3 * wob[3].y;
        ob.z += w0 * wob[0].z + w1 * wob[1].z + w2 * wob[2].z + w3 * wob[3].z;
        ob.w += w0 * wob[0].w + w1 * wob[1].w + w2 * wob[2].w + w3 * wob[3].w;

        float* orow = out + ((size_t)b * Nn + ncur) * Hh;
        union { float4 s; f32x4_t v; } ua, ub;
        ua.s = oa; ub.s = ob;
        __builtin_nontemporal_store(ua.v, (f32x4_t*)(orow + lane * 4));
        __builtin_nontemporal_store(ub.v, (f32x4_t*)(orow + 256 + lane * 4));
    }
}

extern "C" void kernel_launch(void* const* d_in, const int* in_sizes, int n_in,
                              void* d_out, int out_size, void* d_ws, size_t ws_size,
                              hipStream_t stream) {
    const float* x       = (const float*)d_in[0];
    const float* Wq      = (const float*)d_in[1];
    const float* bq      = (const float*)d_in[2];
    const float* Wk      = (const float*)d_in[3];
    const float* bk      = (const float*)d_in[4];
    const float* Wv      = (const float*)d_in[5];
    const float* bv      = (const float*)d_in[6];
    const float* E       = (const float*)d_in[7];
    const float* Fp      = (const float*)d_in[8];
    const float* gbu     = (const float*)d_in[9];
    const float* gbv     = (const float*)d_in[10];
    const float* Wo      = (const float*)d_in[11];
    const float* bo      = (const float*)d_in[12];
    const float* log_reg = (const float*)d_in[13];

    float* out = (float*)d_out;
    float* ws = (float*)d_ws;
    float* xs   = ws;  // reuse XS region at offset 0
    float* ksum = ws + KSUM_OFF;
    float* vsum = ws + VSUM_OFF;
    float* wqe  = ws + WQE_OFF;
    float* woe  = ws + WOE_OFF;
    float* esum = ws + ESUM_OFF;
    float* fsum = ws + FSUM_OFF;
    float* bias_q = ws + BQ_OFF;
    float* bias_diag = ws + BD_OFF;
    float* reg_out = out + (size_t)Bsz * Nn * Hh;

    // scratch: prefer d_ws (keeps d_out write-once); fall back to d_out's head
    // region if ws is small.
    float* xpart;
    float* efpart;
    if (ws_size >= (size_t)WS_NEED * sizeof(float)) {
        xpart  = ws + XPART_OFF;
        efpart = ws + EFPART_OFF;
    } else {
        xpart  = out;
        efpart = out + (size_t)NPART * Bsz * Hh;
    }

    k_part<<<NPART * Bsz + 64, 256, 0, stream>>>(x, E, Fp, xpart, efpart);
    k_reduce<<<17, 256, 0, stream>>>(xpart, efpart, xs, esum, fsum);
    k_gemv<<<dim3(2, 32), 256, 0, stream>>>(Wk, bk, Wv, bv, xs, ksum, vsum);
    k_eff2<<<65, 256, 0, stream>>>(Wq, Wo, ksum, vsum, wqe, woe,
                                   bq, gbu, gbv, log_reg, bias_q, bias_diag, reg_out);
    k_main<<<dim3(250, Bsz), 256, 0, stream>>>(x, bo, wqe, woe, esum, fsum, bias_q, bias_diag, out);
}

// Round 7
// 350.504 us; speedup vs baseline: 1.0156x; 1.0156x over previous
//
#include <hip/hip_runtime.h>
#include <math.h>

#define HEADS 4
#define KB 8
#define Bsz 8
#define Nn 10000
#define Hh 512
#define HD 128   // head dim = Hh/HEADS
#define NPART 128

// ws layout (float offsets)
#define KSUM_OFF 4096      // [B][H]        4096
#define VSUM_OFF 8192      // [B][H]        4096
#define WQE_OFF  12288     // [B][4][H]    16384
#define WOE_OFF  28672     // [B][4][H]    16384
#define ESUM_OFF 45056     // [4][8]          32
#define FSUM_OFF 45088     // [4][8]          32
#define BQ_OFF   45120     // [B][4]          32
#define BD_OFF   45152     // [4][8]          32
#define XPART_OFF 45184                        // [NPART][B][Hh] = 524288 floats
#define EFPART_OFF (XPART_OFF + NPART * Bsz * Hh)
#define WS_NEED   (EFPART_OFF + 512)

typedef float f32x4_t __attribute__((ext_vector_type(4)));

// ---------------- K1: partial sums (atomic-free) ----------------
__global__ __launch_bounds__(256) void k_part(const float* __restrict__ x,
                                              const float* __restrict__ E,
                                              const float* __restrict__ Fp,
                                              float* __restrict__ xpart,
                                              float* __restrict__ efpart) {
    int blk = blockIdx.x;
    int t = threadIdx.x;
    if (blk < NPART * Bsz) {
        int p = blk >> 3, b = blk & 7;
        const int CH = (Nn + NPART - 1) / NPART;  // 79
        int n0 = p * CH, n1 = min(n0 + CH, Nn);
        int c = t * 2;
        float a0 = 0.f, a1 = 0.f;
        const float* base = x + (size_t)b * Nn * Hh + c;
#pragma unroll 8
        for (int n = n0; n < n1; ++n) {
            float2 v = *(const float2*)(base + (size_t)n * Hh);
            a0 += v.x; a1 += v.y;
        }
        float* o = xpart + (size_t)(p * Bsz + b) * Hh;
        o[c] = a0; o[c + 1] = a1;
    } else {
        int idx = blk - NPART * Bsz;  // 0..63
        int src = idx >> 5, h = (idx >> 3) & 3, ch = idx & 7;
        const float* S = src ? Fp : E;
        const int CHE = Nn / 8;  // 1250
        int n0 = ch * CHE, n1 = n0 + CHE;
        int kk = t & 7, part = t >> 3;  // 32 parts
        float acc = 0.f;
        const float* base = S + (size_t)h * Nn * KB;
#pragma unroll 4
        for (int n = n0 + part; n < n1; n += 32) acc += base[n * KB + kk];
        __shared__ float sd[256];
        sd[t] = acc;
        __syncthreads();
        for (int s = 128; s >= 8; s >>= 1) {
            if (t < s) sd[t] += sd[t + s];
            __syncthreads();
        }
        if (t < 8) efpart[idx * 8 + t] = sd[t];
    }
}

// ---------------- K2: reduce partials ----------------
__global__ __launch_bounds__(256) void k_reduce(const float* __restrict__ xpart,
                                                const float* __restrict__ efpart,
                                                float* __restrict__ xs,
                                                float* __restrict__ esum,
                                                float* __restrict__ fsum) {
    int blk = blockIdx.x, t = threadIdx.x;
    if (blk < 16) {
        int o = blk * 256 + t;  // b*512 + c
        float a = 0.f;
#pragma unroll 8
        for (int p = 0; p < NPART; ++p) a += xpart[(size_t)p * (Bsz * Hh) + o];
        xs[o] = a;
    } else if (t < 64) {
        int src = t >> 5, rem = t & 31;  // rem = h*8+kk
        float a = 0.f;
#pragma unroll
        for (int ch = 0; ch < 8; ++ch)
            a += efpart[((src * 4 + (rem >> 3)) * 8 + ch) * 8 + (rem & 7)];
        if (src == 0) esum[rem] = a; else fsum[rem] = a;
    }
}

// ---------------- K3: ksum[b,r] = sum_c Wk[r,c]*xs[b,c] + N*bk[r] ----------------
// grid (2, 32): m selects K/V matrix, rg covers 16 rows; xs register-resident,
// folded butterfly reduces all 8 batches in 10 shuffles.
__global__ __launch_bounds__(256) void k_gemv(const float* __restrict__ Wk,
                                              const float* __restrict__ bk,
                                              const float* __restrict__ Wv,
                                              const float* __restrict__ bv,
                                              const float* __restrict__ xs,
                                              float* __restrict__ ksum,
                                              float* __restrict__ vsum) {
    int m = blockIdx.x;
    int rg = blockIdx.y;  // 0..31
    const float* W = m ? Wv : Wk;
    const float* bias = m ? bv : bk;
    float* outp = m ? vsum : ksum;
    int t = threadIdx.x;
    int wid = t >> 6, lane = t & 63;
    bool hi32 = (lane & 32) != 0;
    bool hi16 = (lane & 16) != 0;
    bool hi8  = (lane & 8) != 0;

    float4 x0[Bsz], x1[Bsz];
#pragma unroll
    for (int b = 0; b < Bsz; ++b) {
        x0[b] = *(const float4*)(xs + b * Hh + lane * 4);
        x1[b] = *(const float4*)(xs + b * Hh + 256 + lane * 4);
    }
#pragma unroll
    for (int i = 0; i < 4; ++i) {
        int r = rg * 16 + wid + 4 * i;
        float4 wa = *(const float4*)(W + (size_t)r * Hh + lane * 4);
        float4 wb = *(const float4*)(W + (size_t)r * Hh + 256 + lane * 4);
        float p[Bsz];
#pragma unroll
        for (int b = 0; b < Bsz; ++b) {
            p[b] = wa.x * x0[b].x + wa.y * x0[b].y + wa.z * x0[b].z + wa.w * x0[b].w +
                   wb.x * x1[b].x + wb.y * x1[b].y + wb.z * x1[b].z + wb.w * x1[b].w;
        }
        // fold 8 accumulators across the wave: lane-group g = lane>>3 ends with batch b=g.
        float a, bb;
        a = hi32 ? p[4] : p[0]; bb = hi32 ? p[0] : p[4]; float q0 = a + __shfl_xor(bb, 32, 64);
        a = hi32 ? p[5] : p[1]; bb = hi32 ? p[1] : p[5]; float q1 = a + __shfl_xor(bb, 32, 64);
        a = hi32 ? p[6] : p[2]; bb = hi32 ? p[2] : p[6]; float q2 = a + __shfl_xor(bb, 32, 64);
        a = hi32 ? p[7] : p[3]; bb = hi32 ? p[3] : p[7]; float q3 = a + __shfl_xor(bb, 32, 64);
        a = hi16 ? q2 : q0; bb = hi16 ? q0 : q2; float r0 = a + __shfl_xor(bb, 16, 64);
        a = hi16 ? q3 : q1; bb = hi16 ? q1 : q3; float r1 = a + __shfl_xor(bb, 16, 64);
        a = hi8 ? r1 : r0; bb = hi8 ? r0 : r1; float s = a + __shfl_xor(bb, 8, 64);
        s += __shfl_xor(s, 4, 64);
        s += __shfl_xor(s, 2, 64);
        s += __shfl_xor(s, 1, 64);
        if ((lane & 7) == 0) {
            int b = lane >> 3;
            outp[b * Hh + r] = s + (float)Nn * bias[r];
        }
    }
}

// ---------------- K4: wq_eff / wo_eff + (block 64) bias_q, bias_diag, reg ----------------
// unroll 16 on the Wq column walk (32 loads in flight vs 8 against ~900cy
// cold-HBM latency), float4 + unroll 8 on the Wo row walk.
__global__ __launch_bounds__(256) void k_eff2(const float* __restrict__ Wq,
                                              const float* __restrict__ Wo,
                                              const float* __restrict__ ksum,
                                              const float* __restrict__ vsum,
                                              float* __restrict__ wqe,
                                              float* __restrict__ woe,
                                              const float* __restrict__ bq,
                                              const float* __restrict__ gbu,
                                              const float* __restrict__ gbv,
                                              const float* __restrict__ log_reg,
                                              float* __restrict__ bias_q,
                                              float* __restrict__ bias_diag,
                                              float* __restrict__ reg_out) {
    int blk = blockIdx.x;
    int t = threadIdx.x;
    __shared__ float sL[256];
    if (blk < 64) {
        int b = blk >> 3, rem = blk & 7, h = rem >> 1, m = rem & 1;
        const float* s = (m ? vsum : ksum) + b * Hh + h * HD;
        float* out = (m ? woe : wqe) + (size_t)(b * HEADS + h) * Hh;
        if (t < HD) sL[t] = s[t];
        __syncthreads();
        float a0 = 0.f, a1 = 0.f;
        if (m == 0) {
            const float* Wb = Wq + (size_t)h * HD * Hh;
#pragma unroll 16
            for (int d = 0; d < HD; ++d) {
                float sv = sL[d];
                a0 += Wb[(size_t)d * Hh + t] * sv;
                a1 += Wb[(size_t)d * Hh + t + 256] * sv;
            }
        } else {
            const float4* W0 = (const float4*)(Wo + (size_t)t * Hh + h * HD);
            const float4* W1 = (const float4*)(Wo + (size_t)(t + 256) * Hh + h * HD);
#pragma unroll 8
            for (int d = 0; d < HD; d += 4) {
                float4 w0 = W0[d >> 2];
                float4 w1 = W1[d >> 2];
                a0 += w0.x * sL[d] + w0.y * sL[d + 1] + w0.z * sL[d + 2] + w0.w * sL[d + 3];
                a1 += w1.x * sL[d] + w1.y * sL[d + 1] + w1.z * sL[d + 2] + w1.w * sL[d + 3];
            }
        }
        out[t] = a0;
        out[t + 256] = a1;
    } else {
        int h = t >> 6, i = (t >> 3) & 7, j = t & 7;
        float gb = 0.f;
#pragma unroll
        for (int l = 0; l < 8; ++l) gb += gbu[h * 64 + i * 8 + l] * gbv[h * 64 + l * 8 + j];
        if (i == j) bias_diag[h * 8 + i] = gb;
        sL[t] = fabsf(gb);
        __syncthreads();
        for (int s = 128; s >= 1; s >>= 1) {
            if (t < s) sL[t] += sL[t + s];
            __syncthreads();
        }
        if (t == 0) {
            float gbmean = sL[0] / 256.f;
            reg_out[0] = expf(log_reg[0]) * (0.125f + gbmean * 0.1f);
        }
        if (t < 32) {
            int b = t >> 2, hh = t & 3;
            float a = 0.f;
            for (int d = 0; d < HD; ++d) a += bq[hh * HD + d] * ksum[b * Hh + hh * HD + d];
            bias_q[t] = a;  // [b][h]
        }
    }
}

// ---------------- K5: main pass (no LDS, all weights in registers) ----------------
// grid (250, B), block 256 = 4 waves; wave-per-row. Non-temporal stores so the
// out-write does not evict x from L3.
__global__ __launch_bounds__(256) void k_main(const float* __restrict__ x,
                                              const float* __restrict__ bo,
                                              const float* __restrict__ wqe,
                                              const float* __restrict__ woe,
                                              const float* __restrict__ esum,
                                              const float* __restrict__ fsum,
                                              const float* __restrict__ bias_q,
                                              const float* __restrict__ bias_diag,
                                              float* __restrict__ out) {
    int b = blockIdx.y;
    int t = threadIdx.x;
    int wid = t >> 6, lane = t & 63;

    const float* wqe_b = wqe + (size_t)b * HEADS * Hh;
    const float* woe_b = woe + (size_t)b * HEADS * Hh;
    float4 wqa[HEADS], wqb[HEADS], woa[HEADS], wob[HEADS];
#pragma unroll
    for (int h = 0; h < HEADS; ++h) {
        wqa[h] = *(const float4*)(wqe_b + h * Hh + lane * 4);
        wqb[h] = *(const float4*)(wqe_b + h * Hh + 256 + lane * 4);
        woa[h] = *(const float4*)(woe_b + h * Hh + lane * 4);
        wob[h] = *(const float4*)(woe_b + h * Hh + 256 + lane * 4);
    }
    float4 boa = *(const float4*)(bo + lane * 4);
    float4 bob = *(const float4*)(bo + 256 + lane * 4);

    // quadrant softmax mapping: quadrant q = lane>>4 holds head hq = {0,2,1,3}[q]
    int q = lane >> 4;
    int hq = (q == 0) ? 0 : (q == 1) ? 2 : (q == 2) ? 1 : 3;
    int kk = lane & 7;
    float eV = esum[hq * KB + kk];
    float fV = fsum[hq * KB + kk];
    float bdV = bias_diag[hq * KB + kk];
    float bqV = bias_q[b * HEADS + hq];

    const float inv_sqrt_hd = 0.08838834764831843f;  // 1/sqrt(128)
    bool hi32 = (lane & 32) != 0;
    bool hi16 = (lane & 16) != 0;

    int n = blockIdx.x * 4 + wid;  // grid.x == 250 -> step 1000, exactly 10 rows/wave
    for (int j = 0; j < 10; ++j, n += 1000) {
        const float* xr = x + ((size_t)b * Nn + n) * Hh;
        float4 xa = *(const float4*)(xr + lane * 4);
        float4 xb = *(const float4*)(xr + 256 + lane * 4);
        float p[HEADS];
#pragma unroll
        for (int h = 0; h < HEADS; ++h) {
            p[h] = xa.x * wqa[h].x + xa.y * wqa[h].y + xa.z * wqa[h].z + xa.w * wqa[h].w +
                   xb.x * wqb[h].x + xb.y * wqb[h].y + xb.z * wqb[h].z + xb.w * wqb[h].w;
        }
        // folded butterfly: 7 shfl instead of 24.
        float A  = hi32 ? p[1] : p[0];
        float Bv = hi32 ? p[0] : p[1];
        A += __shfl_xor(Bv, 32, 64);
        float C  = hi32 ? p[3] : p[2];
        float D  = hi32 ? p[2] : p[3];
        C += __shfl_xor(D, 32, 64);
        float Ev = hi16 ? C : A;
        float Fv = hi16 ? A : C;
        Ev += __shfl_xor(Fv, 16, 64);
        Ev += __shfl_xor(Ev, 1, 64);
        Ev += __shfl_xor(Ev, 2, 64);
        Ev += __shfl_xor(Ev, 4, 64);
        Ev += __shfl_xor(Ev, 8, 64);
        // Ev = full 64-lane dot for head hq, identical across the quadrant

        float sq = (Ev + bqV) * inv_sqrt_hd;
        float sc = eV * sq + bdV;
        float m = sc;
        m = fmaxf(m, __shfl_xor(m, 1, 64));
        m = fmaxf(m, __shfl_xor(m, 2, 64));
        m = fmaxf(m, __shfl_xor(m, 4, 64));
        float e = __expf(sc - m);
        float se = e, sw = e * fV;
        se += __shfl_xor(se, 1, 64); sw += __shfl_xor(sw, 1, 64);
        se += __shfl_xor(se, 2, 64); sw += __shfl_xor(sw, 2, 64);
        se += __shfl_xor(se, 4, 64); sw += __shfl_xor(sw, 4, 64);
        float wv = __fdividef(sw, se);
        float w0 = __shfl(wv, 0, 64);
        float w2 = __shfl(wv, 16, 64);
        float w1 = __shfl(wv, 32, 64);
        float w3 = __shfl(wv, 48, 64);

        float4 oa = boa, ob = bob;
        oa.x += w0 * woa[0].x + w1 * woa[1].x + w2 * woa[2].x + w3 * woa[3].x;
        oa.y += w0 * woa[0].y + w1 * woa[1].y + w2 * woa[2].y + w3 * woa[3].y;
        oa.z += w0 * woa[0].z + w1 * woa[1].z + w2 * woa[2].z + w3 * woa[3].z;
        oa.w += w0 * woa[0].w + w1 * woa[1].w + w2 * woa[2].w + w3 * woa[3].w;
        ob.x += w0 * wob[0].x + w1 * wob[1].x + w2 * wob[2].x + w3 * wob[3].x;
        ob.y += w0 * wob[0].y + w1 * wob[1].y + w2 * wob[2].y + w3 * wob[3].y;
        ob.z += w0 * wob[0].z + w1 * wob[1].z + w2 * wob[2].z + w3 * wob[3].z;
        ob.w += w0 * wob[0].w + w1 * wob[1].w + w2 * wob[2].w + w3 * wob[3].w;

        float* orow = out + ((size_t)b * Nn + n) * Hh;
        union { float4 s; f32x4_t v; } ua, ub;
        ua.s = oa; ub.s = ob;
        __builtin_nontemporal_store(ua.v, (f32x4_t*)(orow + lane * 4));
        __builtin_nontemporal_store(ub.v, (f32x4_t*)(orow + 256 + lane * 4));
    }
}

extern "C" void kernel_launch(void* const* d_in, const int* in_sizes, int n_in,
                              void* d_out, int out_size, void* d_ws, size_t ws_size,
                              hipStream_t stream) {
    const float* x       = (const float*)d_in[0];
    const float* Wq      = (const float*)d_in[1];
    const float* bq      = (const float*)d_in[2];
    const float* Wk      = (const float*)d_in[3];
    const float* bk      = (const float*)d_in[4];
    const float* Wv      = (const float*)d_in[5];
    const float* bv      = (const float*)d_in[6];
    const float* E       = (const float*)d_in[7];
    const float* Fp      = (const float*)d_in[8];
    const float* gbu     = (const float*)d_in[9];
    const float* gbv     = (const float*)d_in[10];
    const float* Wo      = (const float*)d_in[11];
    const float* bo      = (const float*)d_in[12];
    const float* log_reg = (const float*)d_in[13];

    float* out = (float*)d_out;
    float* ws = (float*)d_ws;
    float* xs   = ws;  // reuse XS region at offset 0
    float* ksum = ws + KSUM_OFF;
    float* vsum = ws + VSUM_OFF;
    float* wqe  = ws + WQE_OFF;
    float* woe  = ws + WOE_OFF;
    float* esum = ws + ESUM_OFF;
    float* fsum = ws + FSUM_OFF;
    float* bias_q = ws + BQ_OFF;
    float* bias_diag = ws + BD_OFF;
    float* reg_out = out + (size_t)Bsz * Nn * Hh;

    // scratch: prefer d_ws (keeps d_out write-once); fall back to d_out's head
    // region if ws is small.
    float* xpart;
    float* efpart;
    if (ws_size >= (size_t)WS_NEED * sizeof(float)) {
        xpart  = ws + XPART_OFF;
        efpart = ws + EFPART_OFF;
    } else {
        xpart  = out;
        efpart = out + (size_t)NPART * Bsz * Hh;
    }

    k_part<<<NPART * Bsz + 64, 256, 0, stream>>>(x, E, Fp, xpart, efpart);
    k_reduce<<<17, 256, 0, stream>>>(xpart, efpart, xs, esum, fsum);
    k_gemv<<<dim3(2, 32), 256, 0, stream>>>(Wk, bk, Wv, bv, xs, ksum, vsum);
    k_eff2<<<65, 256, 0, stream>>>(Wq, Wo, ksum, vsum, wqe, woe,
                                   bq, gbu, gbv, log_reg, bias_q, bias_diag, reg_out);
    k_main<<<dim3(250, Bsz), 256, 0, stream>>>(x, bo, wqe, woe, esum, fsum, bias_q, bias_diag, out);
}